// Round 2
// baseline (661.567 us; speedup 1.0000x reference)
//
#include <hip/hip_runtime.h>

#define HW_  262144     // 512*512
#define C_   64
#define HID_ 128
#define K_   16
#define B_   4
#define NPIX (B_*HW_)   // 1048576

// ws float layout:
// [0,256)        accum [b][k][4] = (r,g,b,count) fp32, atomically accumulated
// [256,8448)     W1f  [o][c]   fp32
// [8448,8576)    b1f  [o]      fp32
// [8576,10624)   W2T  [o][k]   fp32 (transposed for contiguous per-o reads)
// [10624,10816)  palette fp32 [b][k][3]

__global__ __launch_bounds__(256) void prep_kernel(
    const float* __restrict__ W1, const float* __restrict__ b1,
    const float* __restrict__ W2, float* __restrict__ wsf)
{
    int t = threadIdx.x;
    wsf[t] = 0.0f;                       // zero the 256 accum slots
    for (int i = t; i < HID_*C_; i += 256)
        wsf[256 + i] = W1[i];
    if (t < HID_)
        wsf[8448 + t] = b1[t];
    for (int i = t; i < K_*HID_; i += 256) {
        int k = i / HID_, o = i % HID_;
        wsf[8576 + o*K_ + k] = W2[i];
    }
}

__global__ __launch_bounds__(256) void mlp_kernel(
    const float* __restrict__ feat, const float* __restrict__ img,
    const float* __restrict__ wsf, float* __restrict__ m_out,
    float* __restrict__ accum)
{
    __shared__ float bins[K_*4];
    int t = threadIdx.x;
    if (t < K_*4) bins[t] = 0.0f;
    __syncthreads();

    int g = blockIdx.x*256 + t;
    int b = g >> 18;             // HW_ == 2^18; blocks never straddle batches
    int p = g & (HW_-1);

    // load this pixel's 64 feature channels (coalesced across lanes per channel)
    const float* fp = feat + ((size_t)(b*C_) << 18) + p;
    float f[C_];
#pragma unroll
    for (int c = 0; c < C_; ++c)
        f[c] = fp[(size_t)c << 18];

    const float* __restrict__ W1f = wsf + 256;
    const float* __restrict__ b1f = wsf + 8448;
    const float* __restrict__ W2T = wsf + 8576;

    float logits[K_];
#pragma unroll
    for (int k = 0; k < K_; ++k) logits[k] = 0.0f;

    // fused layer1 (relu) + layer2; weight loads are wave-uniform -> scalar path
    for (int o = 0; o < HID_; ++o) {
        float h = b1f[o];
#pragma unroll
        for (int c = 0; c < C_; ++c)
            h = fmaf(f[c], W1f[o*C_ + c], h);
        h = fmaxf(h, 0.0f);
#pragma unroll
        for (int k = 0; k < K_; ++k)
            logits[k] = fmaf(h, W2T[o*K_ + k], logits[k]);
    }

    // argmax (first index wins on ties, matching np.argmax)
    float lmax = logits[0];
    int kstar = 0;
#pragma unroll
    for (int k = 1; k < K_; ++k)
        if (logits[k] > lmax) { lmax = logits[k]; kstar = k; }

    // softmax(1e4 * logits), max-subtracted like jax.nn.softmax
    float ex[K_];
    float esum = 0.0f;
#pragma unroll
    for (int k = 0; k < K_; ++k) {
        ex[k] = __expf(1.0e4f * (logits[k] - lmax));
        esum += ex[k];
    }
    float inv = 1.0f / esum;
#pragma unroll
    for (int k = 0; k < K_; ++k)
        m_out[((size_t)(b*K_ + k) << 18) + p] = ex[k] * inv;

    // palette accumulation: LDS bins first, then one global atomic per slot
    const float* ip = img + ((size_t)(b*3) << 18) + p;
    atomicAdd(&bins[kstar*4+0], ip[0]);
    atomicAdd(&bins[kstar*4+1], ip[(size_t)1 << 18]);
    atomicAdd(&bins[kstar*4+2], ip[(size_t)2 << 18]);
    atomicAdd(&bins[kstar*4+3], 1.0f);
    __syncthreads();
    if (t < K_*4)
        atomicAdd(&accum[b*K_*4 + t], bins[t]);
}

__global__ __launch_bounds__(64) void palette_kernel(
    const float* __restrict__ accum, float* __restrict__ pal_out,
    float* __restrict__ palf)
{
    int t = threadIdx.x;   // 0..63 == b*16+k
    float den  = accum[t*4+3];
    float invd = 1.0f / (den + 1e-8f);
#pragma unroll
    for (int c = 0; c < 3; ++c) {
        float pal = accum[t*4+c] * invd;
        palf[t*3+c]    = pal;
        pal_out[t*3+c] = pal;
    }
}

__global__ __launch_bounds__(256) void recolor_kernel(
    const float* __restrict__ m_in, const float* __restrict__ palf,
    float* __restrict__ timg)
{
    int g = blockIdx.x*256 + threadIdx.x;
    int b = g >> 18;
    int p = g & (HW_-1);
    const float* mp = m_in + ((size_t)(b*K_) << 18) + p;
    float best = -1.0f;
    int ks = 0;
#pragma unroll
    for (int k = 0; k < K_; ++k) {
        float v = mp[(size_t)k << 18];
        if (v > best) { best = v; ks = k; }  // strict > keeps first max, like np.argmax
    }
#pragma unroll
    for (int c = 0; c < 3; ++c)
        timg[((size_t)(b*3+c) << 18) + p] = palf[(b*K_ + ks)*3 + c];
}

extern "C" void kernel_launch(void* const* d_in, const int* in_sizes, int n_in,
                              void* d_out, int out_size, void* d_ws, size_t ws_size,
                              hipStream_t stream)
{
    const float* img  = (const float*)d_in[0];
    const float* feat = (const float*)d_in[1];
    const float* W1   = (const float*)d_in[2];
    const float* b1   = (const float*)d_in[3];
    const float* W2   = (const float*)d_in[4];
    // d_in[5] = training (int32, always 0): eval path only.

    float* out0 = (float*)d_out;                  // transformed_img (B,3,H,W)
    float* out1 = out0 + (size_t)B_*3*HW_;        // m (B,K,H,W)
    float* out2 = out1 + (size_t)B_*K_*HW_;       // color_palette (B,K,3,1,1)
    float* wsf  = (float*)d_ws;

    prep_kernel<<<1, 256, 0, stream>>>(W1, b1, W2, wsf);
    mlp_kernel<<<NPIX/256, 256, 0, stream>>>(feat, img, wsf, out1, wsf);
    palette_kernel<<<1, 64, 0, stream>>>(wsf, out2, wsf + 10624);
    recolor_kernel<<<NPIX/256, 256, 0, stream>>>(out1, wsf + 10624, out0);
}

// Round 3
// 659.336 us; speedup vs baseline: 1.0034x; 1.0034x over previous
//
#include <hip/hip_runtime.h>

#define HW_  262144     // 512*512
#define C_   64
#define HID_ 128
#define K_   16
#define B_   4
#define NPIX (B_*HW_)   // 1048576

// ws float layout:
// [0,256)        accum [b][k][4] = (r,g,b,count) fp32, atomically accumulated
// [256,8448)     W1f  [o][c]   fp32
// [8448,8576)    b1f  [o]      fp32
// [8576,10624)   W2T  [o][k]   fp32 (transposed for contiguous per-o reads)
// [10624,10816)  palette fp32 [b][k][3]
// [10816,...)    label map, 1 int per pixel (NPIX ints) -- if ws is big enough
#define LBL_OFF 10816
#define WS_NEED ((size_t)(LBL_OFF + NPIX) * 4)

__global__ __launch_bounds__(256) void prep_kernel(
    const float* __restrict__ W1, const float* __restrict__ b1,
    const float* __restrict__ W2, float* __restrict__ wsf)
{
    int t = threadIdx.x;
    wsf[t] = 0.0f;                       // zero the 256 accum slots
    for (int i = t; i < HID_*C_; i += 256)
        wsf[256 + i] = W1[i];
    if (t < HID_)
        wsf[8448 + t] = b1[t];
    for (int i = t; i < K_*HID_; i += 256) {
        int k = i / HID_, o = i % HID_;
        wsf[8576 + o*K_ + k] = W2[i];
    }
}

template<bool WRITE_LABELS>
__global__ __launch_bounds__(256) void mlp_kernel(
    const float* __restrict__ feat, const float* __restrict__ img,
    const float* __restrict__ wsf, float* __restrict__ m_out,
    float* __restrict__ accum, int* __restrict__ labels)
{
    __shared__ float bins[K_*4];
    int t = threadIdx.x;
    if (t < K_*4) bins[t] = 0.0f;
    __syncthreads();

    int g = blockIdx.x*256 + t;
    int b = g >> 18;             // HW_ == 2^18; blocks never straddle batches
    int p = g & (HW_-1);

    // load this pixel's 64 feature channels (coalesced across lanes per channel)
    const float* fp = feat + ((size_t)(b*C_) << 18) + p;
    float f[C_];
#pragma unroll
    for (int c = 0; c < C_; ++c)
        f[c] = fp[(size_t)c << 18];
    // Pin the features in VGPRs: forbids the compiler from sinking /
    // rematerializing these global loads inside the o-loop (round-1 showed
    // VGPR_Count=44 => f[] was reloaded ~128x from memory, VMEM-issue-bound).
#pragma unroll
    for (int c = 0; c < C_; ++c)
        asm volatile("" : "+v"(f[c]));

    const float* __restrict__ W1f = wsf + 256;
    const float* __restrict__ b1f = wsf + 8448;
    const float* __restrict__ W2T = wsf + 8576;

    float logits[K_];
#pragma unroll
    for (int k = 0; k < K_; ++k) logits[k] = 0.0f;

    // fused layer1 (relu) + layer2; weight loads are wave-uniform -> SGPR path
    for (int o = 0; o < HID_; ++o) {
        float h = b1f[o];
#pragma unroll
        for (int c = 0; c < C_; ++c)
            h = fmaf(f[c], W1f[o*C_ + c], h);
        h = fmaxf(h, 0.0f);
#pragma unroll
        for (int k = 0; k < K_; ++k)
            logits[k] = fmaf(h, W2T[o*K_ + k], logits[k]);
    }

    // argmax (first index wins on ties, matching np.argmax)
    float lmax = logits[0];
    int kstar = 0;
#pragma unroll
    for (int k = 1; k < K_; ++k)
        if (logits[k] > lmax) { lmax = logits[k]; kstar = k; }

    // softmax(1e4 * logits), max-subtracted like jax.nn.softmax
    float ex[K_];
    float esum = 0.0f;
#pragma unroll
    for (int k = 0; k < K_; ++k) {
        ex[k] = __expf(1.0e4f * (logits[k] - lmax));
        esum += ex[k];
    }
    float inv = 1.0f / esum;
#pragma unroll
    for (int k = 0; k < K_; ++k)
        m_out[((size_t)(b*K_ + k) << 18) + p] = ex[k] * inv;

    if (WRITE_LABELS)
        labels[g] = kstar;

    // palette accumulation: LDS bins first, then one global atomic per slot
    const float* ip = img + ((size_t)(b*3) << 18) + p;
    atomicAdd(&bins[kstar*4+0], ip[0]);
    atomicAdd(&bins[kstar*4+1], ip[(size_t)1 << 18]);
    atomicAdd(&bins[kstar*4+2], ip[(size_t)2 << 18]);
    atomicAdd(&bins[kstar*4+3], 1.0f);
    __syncthreads();
    if (t < K_*4)
        atomicAdd(&accum[b*K_*4 + t], bins[t]);
}

__global__ __launch_bounds__(64) void palette_kernel(
    const float* __restrict__ accum, float* __restrict__ pal_out,
    float* __restrict__ palf)
{
    int t = threadIdx.x;   // 0..63 == b*16+k
    float den  = accum[t*4+3];
    float invd = 1.0f / (den + 1e-8f);
#pragma unroll
    for (int c = 0; c < 3; ++c) {
        float pal = accum[t*4+c] * invd;
        palf[t*3+c]    = pal;
        pal_out[t*3+c] = pal;
    }
}

// fast path: gather palette color by precomputed label (1 int read vs 16 m reads)
__global__ __launch_bounds__(256) void recolor_lbl_kernel(
    const int* __restrict__ labels, const float* __restrict__ palf,
    float* __restrict__ timg)
{
    int g = blockIdx.x*256 + threadIdx.x;
    int b = g >> 18;
    int p = g & (HW_-1);
    int ks = labels[g];
#pragma unroll
    for (int c = 0; c < 3; ++c)
        timg[((size_t)(b*3+c) << 18) + p] = palf[(b*K_ + ks)*3 + c];
}

// fallback path: re-derive argmax from m (used only if ws too small for labels)
__global__ __launch_bounds__(256) void recolor_m_kernel(
    const float* __restrict__ m_in, const float* __restrict__ palf,
    float* __restrict__ timg)
{
    int g = blockIdx.x*256 + threadIdx.x;
    int b = g >> 18;
    int p = g & (HW_-1);
    const float* mp = m_in + ((size_t)(b*K_) << 18) + p;
    float best = -1.0f;
    int ks = 0;
#pragma unroll
    for (int k = 0; k < K_; ++k) {
        float v = mp[(size_t)k << 18];
        if (v > best) { best = v; ks = k; }
    }
#pragma unroll
    for (int c = 0; c < 3; ++c)
        timg[((size_t)(b*3+c) << 18) + p] = palf[(b*K_ + ks)*3 + c];
}

extern "C" void kernel_launch(void* const* d_in, const int* in_sizes, int n_in,
                              void* d_out, int out_size, void* d_ws, size_t ws_size,
                              hipStream_t stream)
{
    const float* img  = (const float*)d_in[0];
    const float* feat = (const float*)d_in[1];
    const float* W1   = (const float*)d_in[2];
    const float* b1   = (const float*)d_in[3];
    const float* W2   = (const float*)d_in[4];
    // d_in[5] = training (int32, always 0): eval path only.

    float* out0 = (float*)d_out;                  // transformed_img (B,3,H,W)
    float* out1 = out0 + (size_t)B_*3*HW_;        // m (B,K,H,W)
    float* out2 = out1 + (size_t)B_*K_*HW_;       // color_palette (B,K,3,1,1)
    float* wsf  = (float*)d_ws;
    int*   lbl  = (int*)(wsf + LBL_OFF);

    const bool use_labels = (ws_size >= WS_NEED);

    prep_kernel<<<1, 256, 0, stream>>>(W1, b1, W2, wsf);
    if (use_labels) {
        mlp_kernel<true><<<NPIX/256, 256, 0, stream>>>(feat, img, wsf, out1, wsf, lbl);
        palette_kernel<<<1, 64, 0, stream>>>(wsf, out2, wsf + 10624);
        recolor_lbl_kernel<<<NPIX/256, 256, 0, stream>>>(lbl, wsf + 10624, out0);
    } else {
        mlp_kernel<false><<<NPIX/256, 256, 0, stream>>>(feat, img, wsf, out1, wsf, lbl);
        palette_kernel<<<1, 64, 0, stream>>>(wsf, out2, wsf + 10624);
        recolor_m_kernel<<<NPIX/256, 256, 0, stream>>>(out1, wsf + 10624, out0);
    }
}

// Round 4
// 533.420 us; speedup vs baseline: 1.2402x; 1.2361x over previous
//
#include <hip/hip_runtime.h>

#define HW_  262144     // 512*512
#define C_   64
#define HID_ 128
#define K_   16
#define B_   4
#define NPIX (B_*HW_)   // 1048576

typedef __attribute__((ext_vector_type(8)))  short bf16x8;   // 8 bf16 = 4 VGPR
typedef __attribute__((ext_vector_type(16))) float f32x16;   // 32x32 C/D frag
typedef __attribute__((ext_vector_type(4)))  short short4v;  // 8B LDS store

// ---------- fast-path ws byte layout ----------
// [0,1024)          accum [b][k][4] fp32
// [1024,1792)       palette fp32 [b][k][3]
// [2048,34816)      W1 A-frags  (m,s)x{hi,lo}: 32 frags x 1KB  (bf16)
// [34816,51200)     W2 A-frags  (t)x{hi,lo}:   16 frags x 1KB  (bf16, k>=16 zero-pad)
// [51200,...)       labels, NPIX int
#define W1F_BYTE 2048
#define W2F_BYTE 34816
#define LBL_BYTE 51200
#define WS_NEED_FAST ((size_t)LBL_BYTE + (size_t)NPIX*4)

__device__ __forceinline__ unsigned short f2bf(float x) {       // RNE fp32->bf16
    unsigned u = __float_as_uint(x);
    unsigned r = u + 0x7FFFu + ((u >> 16) & 1u);
    return (unsigned short)(r >> 16);
}
__device__ __forceinline__ float bf2f(unsigned short h) {
    return __uint_as_float(((unsigned)h) << 16);
}
__device__ __forceinline__ f32x16 mfma32(bf16x8 a, bf16x8 b, f32x16 c) {
    return __builtin_amdgcn_mfma_f32_32x32x16_bf16(a, b, c, 0, 0, 0);
}

// ================= fast path =================

// grid 48 x 256: zero accum + build W1/W2 frags (hi/lo split)
__global__ __launch_bounds__(256) void prep_fast(
    const float* __restrict__ W1, const float* __restrict__ W2,
    float* __restrict__ wsf)
{
    int gi = blockIdx.x*256 + threadIdx.x;
    if (gi < 256) wsf[gi] = 0.0f;                       // accum
    unsigned short* w1f = (unsigned short*)((char*)wsf + W1F_BYTE);
    unsigned short* w2f = (unsigned short*)((char*)wsf + W2F_BYTE);
    if (gi < 8192) {                                    // W1 frag elem
        int j = gi & 7, l = (gi >> 3) & 63, s = (gi >> 9) & 3, m = (gi >> 11) & 3;
        int o = 32*m + (l & 31);
        int c = 16*s + 8*(l >> 5) + j;
        float w  = W1[o*C_ + c];
        unsigned short hi = f2bf(w);
        unsigned short lo = f2bf(w - bf2f(hi));
        int base = ((m*4 + s)*2)*512 + l*8 + j;
        w1f[base]       = hi;
        w1f[base + 512] = lo;
    } else if (gi < 12288) {                            // W2 frag elem
        int i = gi - 8192;
        int j = i & 7, l = (i >> 3) & 63, t = (i >> 9) & 7;
        int k = l & 31;
        int o = 16*t + 8*(l >> 5) + j;
        float w = (k < K_) ? W2[k*HID_ + o] : 0.0f;
        unsigned short hi = f2bf(w);
        unsigned short lo = f2bf(w - bf2f(hi));
        int base = (t*2)*512 + l*8 + j;
        w2f[base]       = hi;
        w2f[base + 512] = lo;
    }
}

// 128 px / block (4 waves x 32 px). Split-bf16 MFMA MLP, fused softmax/argmax.
__global__ __launch_bounds__(256, 2) void mlp_mfma(
    const float* __restrict__ feat, const float* __restrict__ img,
    const float* __restrict__ b1,
    const unsigned short* __restrict__ w1f, const unsigned short* __restrict__ w2f,
    float* __restrict__ m_out, float* __restrict__ accum, int* __restrict__ labels)
{
    __shared__ float b1s[HID_];
    __shared__ float bins[K_*4];
    __shared__ short hhi[4][32][72];   // per-wave h chunk (o in [0,64)), stride 72: 16B-aligned reads
    __shared__ short hlo[4][32][72];

    int t = threadIdx.x, lane = t & 63, w = t >> 6;
    int col = lane & 31, half = lane >> 5;
    if (t < HID_) b1s[t] = b1[t];
    if (t < K_*4) bins[t] = 0.0f;
    __syncthreads();

    int blk = blockIdx.x;
    int b   = blk >> 11;                       // 2048 blocks per batch
    int px0 = (blk & 2047)*128 + w*32;         // pixel base within batch
    int px  = px0 + col;
    const float* fb = feat + ((size_t)b*C_ << 18) + px;

    // ---------- layer 1: h[o][px] = relu(W1 feat + b1), split-bf16 MFMA ----------
    f32x16 acc[4];
#pragma unroll
    for (int m = 0; m < 4; ++m) acc[m] = 0.0f;

    const bf16x8* w1v = (const bf16x8*)w1f;
#pragma unroll
    for (int s = 0; s < 4; ++s) {
        int c0 = 16*s + 8*half;
        float fv[8];
#pragma unroll
        for (int j = 0; j < 8; ++j)
            fv[j] = fb[(size_t)(c0 + j) << 18];
        bf16x8 bh, bl;
#pragma unroll
        for (int j = 0; j < 8; ++j) {
            unsigned short hi = f2bf(fv[j]);
            bh[j] = (short)hi;
            bl[j] = (short)f2bf(fv[j] - bf2f(hi));
        }
#pragma unroll
        for (int m = 0; m < 4; ++m) {
            const bf16x8* p = w1v + ((m*4 + s)*2)*64 + lane;
            bf16x8 ah = p[0];      // hi frag
            bf16x8 al = p[64];     // lo frag
            acc[m] = mfma32(ah, bh, acc[m]);
            acc[m] = mfma32(al, bh, acc[m]);
            acc[m] = mfma32(ah, bl, acc[m]);
        }
    }

    // ---------- layer 2: logits[k][px] = W2 h, via per-wave LDS round-trip ----------
    f32x16 acc2 = 0.0f;
    const bf16x8* w2v = (const bf16x8*)w2f;
#pragma unroll
    for (int chunk = 0; chunk < 2; ++chunk) {
        // write h for o in [64*chunk, 64*chunk+64) -> hhi/hlo[w][px][o_local]
#pragma unroll
        for (int ml = 0; ml < 2; ++ml) {
            int m = chunk*2 + ml;
#pragma unroll
            for (int q = 0; q < 4; ++q) {
                short4v vh, vl;
#pragma unroll
                for (int i = 0; i < 4; ++i) {
                    int r = q*4 + i;
                    int o = 32*m + 8*q + 4*half + i;          // global o row
                    float hval = fmaxf(acc[m][r] + b1s[o], 0.0f);
                    unsigned short hi = f2bf(hval);
                    vh[i] = (short)hi;
                    vl[i] = (short)f2bf(hval - bf2f(hi));
                }
                int ob = 32*ml + 8*q + 4*half;                // o within chunk
                *(short4v*)&hhi[w][col][ob] = vh;
                *(short4v*)&hlo[w][col][ob] = vl;
            }
        }
#pragma unroll
        for (int tt = 0; tt < 4; ++tt) {
            int tg = chunk*4 + tt;
            bf16x8 bh2 = *(const bf16x8*)&hhi[w][col][tt*16 + 8*half];
            bf16x8 bl2 = *(const bf16x8*)&hlo[w][col][tt*16 + 8*half];
            const bf16x8* p = w2v + (tg*2)*64 + lane;
            bf16x8 ah = p[0];
            bf16x8 al = p[64];
            acc2 = mfma32(ah, bh2, acc2);
            acc2 = mfma32(al, bh2, acc2);
            acc2 = mfma32(ah, bl2, acc2);
        }
    }

    // ---------- softmax(1e4*logits) + argmax; valid k rows are regs 0..7 ----------
    float lg[8]; int kk[8];
#pragma unroll
    for (int r = 0; r < 8; ++r) {
        lg[r] = acc2[r];
        kk[r] = (r & 3) + 8*(r >> 2) + 4*half;    // ascending within lane
    }
    float mx = lg[0]; int ki = kk[0];
#pragma unroll
    for (int r = 1; r < 8; ++r)
        if (lg[r] > mx) { mx = lg[r]; ki = kk[r]; }
    float mxo = __shfl_xor(mx, 32);
    int   kio = __shfl_xor(ki, 32);
    if (mxo > mx || (mxo == mx && kio < ki)) { mx = mxo; ki = kio; }

    float es[8], ss = 0.0f;
#pragma unroll
    for (int r = 0; r < 8; ++r) {
        es[r] = __expf(1.0e4f * (lg[r] - mx));
        ss += es[r];
    }
    ss += __shfl_xor(ss, 32);
    float inv = 1.0f / ss;                         // global max term gives ss >= 1

    size_t mbase = (size_t)(b*K_) << 18;
#pragma unroll
    for (int r = 0; r < 8; ++r)
        m_out[mbase + ((size_t)kk[r] << 18) + px] = es[r] * inv;

    if (half == 0) {
        labels[((size_t)b << 18) + px] = ki;
        const float* ip = img + ((size_t)(b*3) << 18) + px;
        atomicAdd(&bins[ki*4+0], ip[0]);
        atomicAdd(&bins[ki*4+1], ip[(size_t)1 << 18]);
        atomicAdd(&bins[ki*4+2], ip[(size_t)2 << 18]);
        atomicAdd(&bins[ki*4+3], 1.0f);
    }
    __syncthreads();
    if (t < K_*4) atomicAdd(&accum[b*K_*4 + t], bins[t]);
}

__global__ __launch_bounds__(64) void palette_kernel(
    const float* __restrict__ accum, float* __restrict__ pal_out,
    float* __restrict__ palf)
{
    int t = threadIdx.x;   // b*16+k
    float den  = accum[t*4+3];
    float invd = 1.0f / (den + 1e-8f);
#pragma unroll
    for (int c = 0; c < 3; ++c) {
        float pal = accum[t*4+c] * invd;
        palf[t*3+c]    = pal;
        pal_out[t*3+c] = pal;
    }
}

__global__ __launch_bounds__(256) void recolor_lbl_kernel(
    const int* __restrict__ labels, const float* __restrict__ palf,
    float* __restrict__ timg)
{
    int g = blockIdx.x*256 + threadIdx.x;
    int b = g >> 18;
    int p = g & (HW_-1);
    int ks = labels[g];
#pragma unroll
    for (int c = 0; c < 3; ++c)
        timg[((size_t)(b*3+c) << 18) + p] = palf[(b*K_ + ks)*3 + c];
}

// ================= scalar fallback (round-3 code, known-passing) =================
// ws: [0,256) accum | [256,8448) W1f | [8448,8576) b1f | [8576,10624) W2T | [10624,10816) palette

__global__ __launch_bounds__(256) void prep_scalar(
    const float* __restrict__ W1, const float* __restrict__ b1,
    const float* __restrict__ W2, float* __restrict__ wsf)
{
    int t = threadIdx.x;
    wsf[t] = 0.0f;
    for (int i = t; i < HID_*C_; i += 256) wsf[256 + i] = W1[i];
    if (t < HID_) wsf[8448 + t] = b1[t];
    for (int i = t; i < K_*HID_; i += 256) {
        int k = i / HID_, o = i % HID_;
        wsf[8576 + o*K_ + k] = W2[i];
    }
}

__global__ __launch_bounds__(256) void mlp_scalar(
    const float* __restrict__ feat, const float* __restrict__ img,
    const float* __restrict__ wsf, float* __restrict__ m_out,
    float* __restrict__ accum)
{
    __shared__ float bins[K_*4];
    int t = threadIdx.x;
    if (t < K_*4) bins[t] = 0.0f;
    __syncthreads();
    int g = blockIdx.x*256 + t;
    int b = g >> 18, p = g & (HW_-1);
    const float* fp = feat + ((size_t)(b*C_) << 18) + p;
    float f[C_];
#pragma unroll
    for (int c = 0; c < C_; ++c) f[c] = fp[(size_t)c << 18];
    const float* W1f = wsf + 256;
    const float* b1f = wsf + 8448;
    const float* W2T = wsf + 8576;
    float logits[K_];
#pragma unroll
    for (int k = 0; k < K_; ++k) logits[k] = 0.0f;
    for (int o = 0; o < HID_; ++o) {
        float h = b1f[o];
#pragma unroll
        for (int c = 0; c < C_; ++c) h = fmaf(f[c], W1f[o*C_ + c], h);
        h = fmaxf(h, 0.0f);
#pragma unroll
        for (int k = 0; k < K_; ++k) logits[k] = fmaf(h, W2T[o*K_ + k], logits[k]);
    }
    float lmax = logits[0]; int kstar = 0;
#pragma unroll
    for (int k = 1; k < K_; ++k)
        if (logits[k] > lmax) { lmax = logits[k]; kstar = k; }
    float ex[K_], esum = 0.0f;
#pragma unroll
    for (int k = 0; k < K_; ++k) { ex[k] = __expf(1.0e4f*(logits[k]-lmax)); esum += ex[k]; }
    float inv = 1.0f / esum;
#pragma unroll
    for (int k = 0; k < K_; ++k)
        m_out[((size_t)(b*K_ + k) << 18) + p] = ex[k] * inv;
    const float* ip = img + ((size_t)(b*3) << 18) + p;
    atomicAdd(&bins[kstar*4+0], ip[0]);
    atomicAdd(&bins[kstar*4+1], ip[(size_t)1 << 18]);
    atomicAdd(&bins[kstar*4+2], ip[(size_t)2 << 18]);
    atomicAdd(&bins[kstar*4+3], 1.0f);
    __syncthreads();
    if (t < K_*4) atomicAdd(&accum[b*K_*4 + t], bins[t]);
}

__global__ __launch_bounds__(256) void recolor_m_kernel(
    const float* __restrict__ m_in, const float* __restrict__ palf,
    float* __restrict__ timg)
{
    int g = blockIdx.x*256 + threadIdx.x;
    int b = g >> 18, p = g & (HW_-1);
    const float* mp = m_in + ((size_t)(b*K_) << 18) + p;
    float best = -1.0f; int ks = 0;
#pragma unroll
    for (int k = 0; k < K_; ++k) {
        float v = mp[(size_t)k << 18];
        if (v > best) { best = v; ks = k; }
    }
#pragma unroll
    for (int c = 0; c < 3; ++c)
        timg[((size_t)(b*3+c) << 18) + p] = palf[(b*K_ + ks)*3 + c];
}

extern "C" void kernel_launch(void* const* d_in, const int* in_sizes, int n_in,
                              void* d_out, int out_size, void* d_ws, size_t ws_size,
                              hipStream_t stream)
{
    const float* img  = (const float*)d_in[0];
    const float* feat = (const float*)d_in[1];
    const float* W1   = (const float*)d_in[2];
    const float* b1   = (const float*)d_in[3];
    const float* W2   = (const float*)d_in[4];

    float* out0 = (float*)d_out;                  // transformed_img (B,3,H,W)
    float* out1 = out0 + (size_t)B_*3*HW_;        // m (B,K,H,W)
    float* out2 = out1 + (size_t)B_*K_*HW_;       // color_palette (B,K,3,1,1)
    float* wsf  = (float*)d_ws;

    if (ws_size >= WS_NEED_FAST) {
        const unsigned short* w1f = (const unsigned short*)((char*)d_ws + W1F_BYTE);
        const unsigned short* w2f = (const unsigned short*)((char*)d_ws + W2F_BYTE);
        int* lbl = (int*)((char*)d_ws + LBL_BYTE);
        float* palf = wsf + 256;                  // byte 1024
        prep_fast<<<48, 256, 0, stream>>>(W1, W2, wsf);
        mlp_mfma<<<NPIX/128, 256, 0, stream>>>(feat, img, b1,
                                               w1f, w2f, out1, wsf, lbl);
        palette_kernel<<<1, 64, 0, stream>>>(wsf, out2, palf);
        recolor_lbl_kernel<<<NPIX/256, 256, 0, stream>>>(lbl, palf, out0);
    } else {
        prep_scalar<<<1, 256, 0, stream>>>(W1, b1, W2, wsf);
        mlp_scalar<<<NPIX/256, 256, 0, stream>>>(feat, img, wsf, out1, wsf);
        palette_kernel<<<1, 64, 0, stream>>>(wsf, out2, wsf + 10624);
        recolor_m_kernel<<<NPIX/256, 256, 0, stream>>>(out1, wsf + 10624, out0);
    }
}

// Round 5
// 514.499 us; speedup vs baseline: 1.2858x; 1.0368x over previous
//
#include <hip/hip_runtime.h>

#define HW_  262144     // 512*512
#define C_   64
#define HID_ 128
#define K_   16
#define B_   4
#define NPIX (B_*HW_)   // 1048576

typedef __attribute__((ext_vector_type(8)))  short bf16x8;   // 8 bf16 = 4 VGPR
typedef __attribute__((ext_vector_type(16))) float f32x16;   // 32x32 C/D frag

// ---------- fast-path ws byte layout ----------
// [0,1024)          accum [b][k][4] fp32
// [1024,1792)       palette fp32 [b][k][3]
// [2048,34816)      W1 A-frags  (m,s)x{hi,lo}: 32 frags x 1KB  (bf16)
// [34816,51200)     W2 A-frags  (t)x{hi,lo}:   16 frags x 1KB  (bf16, k>=16 zero-pad)
// [51200,...)       labels, NPIX int
#define W1F_BYTE 2048
#define W2F_BYTE 34816
#define LBL_BYTE 51200
#define WS_NEED_FAST ((size_t)LBL_BYTE + (size_t)NPIX*4)

__device__ __forceinline__ unsigned short f2bf(float x) {       // RNE fp32->bf16
    unsigned u = __float_as_uint(x);
    unsigned r = u + 0x7FFFu + ((u >> 16) & 1u);
    return (unsigned short)(r >> 16);
}
__device__ __forceinline__ float bf2f(unsigned short h) {
    return __uint_as_float(((unsigned)h) << 16);
}
__device__ __forceinline__ f32x16 mfma32(bf16x8 a, bf16x8 b, f32x16 c) {
    return __builtin_amdgcn_mfma_f32_32x32x16_bf16(a, b, c, 0, 0, 0);
}

// ================= fast path =================

// grid 48 x 256: zero accum + build W1/W2 frags (hi/lo split).  (validated round 4)
__global__ __launch_bounds__(256) void prep_fast(
    const float* __restrict__ W1, const float* __restrict__ W2,
    float* __restrict__ wsf)
{
    int gi = blockIdx.x*256 + threadIdx.x;
    if (gi < 256) wsf[gi] = 0.0f;                       // accum
    unsigned short* w1f = (unsigned short*)((char*)wsf + W1F_BYTE);
    unsigned short* w2f = (unsigned short*)((char*)wsf + W2F_BYTE);
    if (gi < 8192) {                                    // W1 frag elem
        int j = gi & 7, l = (gi >> 3) & 63, s = (gi >> 9) & 3, m = (gi >> 11) & 3;
        int o = 32*m + (l & 31);
        int c = 16*s + 8*(l >> 5) + j;
        float w  = W1[o*C_ + c];
        unsigned short hi = f2bf(w);
        unsigned short lo = f2bf(w - bf2f(hi));
        int base = ((m*4 + s)*2)*512 + l*8 + j;
        w1f[base]       = hi;
        w1f[base + 512] = lo;
    } else if (gi < 12288) {                            // W2 frag elem
        int i = gi - 8192;
        int j = i & 7, l = (i >> 3) & 63, t = (i >> 9) & 7;
        int k = l & 31;
        int o = 16*t + 8*(l >> 5) + j;
        float w = (k < K_) ? W2[k*HID_ + o] : 0.0f;
        unsigned short hi = f2bf(w);
        unsigned short lo = f2bf(w - bf2f(hi));
        int base = (t*2)*512 + l*8 + j;
        w2f[base]       = hi;
        w2f[base + 512] = lo;
    }
}

// 128 px / block (4 waves x 32 px). Split-bf16 MFMA MLP.
// Layer-2 B-frags built from layer-1 C-frags via shfl_xor(32) — no LDS round-trip.
__global__ __launch_bounds__(256, 3) void mlp_mfma(
    const float* __restrict__ feat, const float* __restrict__ img,
    const float* __restrict__ b1,
    const unsigned short* __restrict__ w1f, const unsigned short* __restrict__ w2f,
    float* __restrict__ m_out, float* __restrict__ accum, int* __restrict__ labels)
{
    __shared__ float b1s[HID_];
    __shared__ float bins[K_*4];

    int t = threadIdx.x, lane = t & 63, w = t >> 6;
    int col = lane & 31, half = lane >> 5;
    if (t < HID_) b1s[t] = b1[t];
    if (t < K_*4) bins[t] = 0.0f;
    __syncthreads();

    int blk = blockIdx.x;
    int b   = blk >> 11;                       // 2048 blocks per batch
    int px  = (blk & 2047)*128 + w*32 + col;
    const float* fb = feat + ((size_t)b*C_ << 18) + px;

    // ---------- layer 1: h[o][px] = W1 feat (+b1, relu later), split-bf16 MFMA ----------
    // hoist ALL 32 feat loads first: full vmcnt overlap, no load->MFMA serialization
    float fv[32];
#pragma unroll
    for (int s = 0; s < 4; ++s)
#pragma unroll
        for (int j = 0; j < 8; ++j)
            fv[s*8 + j] = fb[(size_t)(16*s + 8*half + j) << 18];

    bf16x8 bh[4], bl[4];
#pragma unroll
    for (int s = 0; s < 4; ++s)
#pragma unroll
        for (int j = 0; j < 8; ++j) {
            float x = fv[s*8 + j];
            unsigned short hi = f2bf(x);
            bh[s][j] = (short)hi;
            bl[s][j] = (short)f2bf(x - bf2f(hi));
        }

    f32x16 acc[4];
#pragma unroll
    for (int m = 0; m < 4; ++m) acc[m] = 0.0f;

    const bf16x8* w1v = (const bf16x8*)w1f;
#pragma unroll
    for (int s = 0; s < 4; ++s)
#pragma unroll
        for (int m = 0; m < 4; ++m) {
            const bf16x8* p = w1v + ((m*4 + s)*2)*64 + lane;
            bf16x8 ah = p[0];      // hi frag
            bf16x8 al = p[64];     // lo frag
            acc[m] = mfma32(ah, bh[s], acc[m]);
            acc[m] = mfma32(al, bh[s], acc[m]);
            acc[m] = mfma32(ah, bl[s], acc[m]);
        }

    // ---------- layer 2: logits[k][px] = W2 h, B-frags via shfl_xor(32) ----------
    // C-frag: lane(col,half') reg r holds o = 32m + (r&3) + 8*(r>>2) + 4*half'.
    // B-frag: lane(col,h) elem j needs o = 16tg + 8h + j.
    //   j<4  -> half'=0 source, reg 4*(2sub+h)+j ;  j>=4 -> half'=1 source, same regs.
    // Own lane keeps regs i_keep=4*half+j (of the 8-reg group 8sub..8sub+7),
    // sends i_send=4*(1-half)+j to its partner (lane^32).
    f32x16 acc2 = 0.0f;
    const bf16x8* w2v = (const bf16x8*)w2f;
#pragma unroll
    for (int tg = 0; tg < 8; ++tg) {
        int m = tg >> 1, sub = tg & 1;
        unsigned pk[8];
#pragma unroll
        for (int i = 0; i < 8; ++i) {
            int r = 8*sub + i;
            int o = 32*m + (i & 3) + 16*sub + 8*(i >> 2) + 4*half;
            float hv = fmaxf(acc[m][r] + b1s[o], 0.0f);
            unsigned short hi = f2bf(hv);
            unsigned short lo = f2bf(hv - bf2f(hi));
            pk[i] = ((unsigned)hi) | (((unsigned)lo) << 16);
        }
        bf16x8 bh2, bl2;
#pragma unroll
        for (int j = 0; j < 4; ++j) {
            unsigned ov = half ? pk[j+4] : pk[j];     // own kept value
            unsigned sv = half ? pk[j]   : pk[j+4];   // value partner needs
            unsigned rv = (unsigned)__shfl_xor((int)sv, 32);
            unsigned lowsrc  = half ? rv : ov;        // half'==0 source -> B[j]
            unsigned highsrc = half ? ov : rv;        // half'==1 source -> B[j+4]
            bh2[j]   = (short)(lowsrc  & 0xffffu);
            bl2[j]   = (short)(lowsrc  >> 16);
            bh2[j+4] = (short)(highsrc & 0xffffu);
            bl2[j+4] = (short)(highsrc >> 16);
        }
        const bf16x8* p = w2v + (tg*2)*64 + lane;
        bf16x8 ah = p[0];
        bf16x8 al = p[64];
        acc2 = mfma32(ah, bh2, acc2);
        acc2 = mfma32(al, bh2, acc2);
        acc2 = mfma32(ah, bl2, acc2);
    }

    // ---------- softmax(1e4*logits) + argmax; valid k rows are regs 0..7 ----------
    float lg[8]; int kk[8];
#pragma unroll
    for (int r = 0; r < 8; ++r) {
        lg[r] = acc2[r];
        kk[r] = (r & 3) + 8*(r >> 2) + 4*half;    // ascending within lane
    }
    float mx = lg[0]; int ki = kk[0];
#pragma unroll
    for (int r = 1; r < 8; ++r)
        if (lg[r] > mx) { mx = lg[r]; ki = kk[r]; }
    float mxo = __shfl_xor(mx, 32);
    int   kio = __shfl_xor(ki, 32);
    if (mxo > mx || (mxo == mx && kio < ki)) { mx = mxo; ki = kio; }

    float es[8], ss = 0.0f;
#pragma unroll
    for (int r = 0; r < 8; ++r) {
        es[r] = __expf(1.0e4f * (lg[r] - mx));
        ss += es[r];
    }
    ss += __shfl_xor(ss, 32);
    float inv = 1.0f / ss;

    size_t mbase = (size_t)(b*K_) << 18;
#pragma unroll
    for (int r = 0; r < 8; ++r)
        m_out[mbase + ((size_t)kk[r] << 18) + px] = es[r] * inv;

    if (half == 0) {
        labels[((size_t)b << 18) + px] = ki;
        const float* ip = img + ((size_t)(b*3) << 18) + px;
        atomicAdd(&bins[ki*4+0], ip[0]);
        atomicAdd(&bins[ki*4+1], ip[(size_t)1 << 18]);
        atomicAdd(&bins[ki*4+2], ip[(size_t)2 << 18]);
        atomicAdd(&bins[ki*4+3], 1.0f);
    }
    __syncthreads();
    if (t < K_*4) atomicAdd(&accum[b*K_*4 + t], bins[t]);
}

__global__ __launch_bounds__(64) void palette_kernel(
    const float* __restrict__ accum, float* __restrict__ pal_out,
    float* __restrict__ palf)
{
    int t = threadIdx.x;   // b*16+k
    float den  = accum[t*4+3];
    float invd = 1.0f / (den + 1e-8f);
#pragma unroll
    for (int c = 0; c < 3; ++c) {
        float pal = accum[t*4+c] * invd;
        palf[t*3+c]    = pal;
        pal_out[t*3+c] = pal;
    }
}

__global__ __launch_bounds__(256) void recolor_lbl_kernel(
    const int* __restrict__ labels, const float* __restrict__ palf,
    float* __restrict__ timg)
{
    int g = blockIdx.x*256 + threadIdx.x;
    int b = g >> 18;
    int p = g & (HW_-1);
    int ks = labels[g];
#pragma unroll
    for (int c = 0; c < 3; ++c)
        timg[((size_t)(b*3+c) << 18) + p] = palf[(b*K_ + ks)*3 + c];
}

// ================= scalar fallback (known-passing) =================
__global__ __launch_bounds__(256) void prep_scalar(
    const float* __restrict__ W1, const float* __restrict__ b1,
    const float* __restrict__ W2, float* __restrict__ wsf)
{
    int t = threadIdx.x;
    wsf[t] = 0.0f;
    for (int i = t; i < HID_*C_; i += 256) wsf[256 + i] = W1[i];
    if (t < HID_) wsf[8448 + t] = b1[t];
    for (int i = t; i < K_*HID_; i += 256) {
        int k = i / HID_, o = i % HID_;
        wsf[8576 + o*K_ + k] = W2[i];
    }
}

__global__ __launch_bounds__(256) void mlp_scalar(
    const float* __restrict__ feat, const float* __restrict__ img,
    const float* __restrict__ wsf, float* __restrict__ m_out,
    float* __restrict__ accum)
{
    __shared__ float bins[K_*4];
    int t = threadIdx.x;
    if (t < K_*4) bins[t] = 0.0f;
    __syncthreads();
    int g = blockIdx.x*256 + t;
    int b = g >> 18, p = g & (HW_-1);
    const float* fp = feat + ((size_t)(b*C_) << 18) + p;
    float f[C_];
#pragma unroll
    for (int c = 0; c < C_; ++c) f[c] = fp[(size_t)c << 18];
    const float* W1f = wsf + 256;
    const float* b1f = wsf + 8448;
    const float* W2T = wsf + 8576;
    float logits[K_];
#pragma unroll
    for (int k = 0; k < K_; ++k) logits[k] = 0.0f;
    for (int o = 0; o < HID_; ++o) {
        float h = b1f[o];
#pragma unroll
        for (int c = 0; c < C_; ++c) h = fmaf(f[c], W1f[o*C_ + c], h);
        h = fmaxf(h, 0.0f);
#pragma unroll
        for (int k = 0; k < K_; ++k) logits[k] = fmaf(h, W2T[o*K_ + k], logits[k]);
    }
    float lmax = logits[0]; int kstar = 0;
#pragma unroll
    for (int k = 1; k < K_; ++k)
        if (logits[k] > lmax) { lmax = logits[k]; kstar = k; }
    float ex[K_], esum = 0.0f;
#pragma unroll
    for (int k = 0; k < K_; ++k) { ex[k] = __expf(1.0e4f*(logits[k]-lmax)); esum += ex[k]; }
    float inv = 1.0f / esum;
#pragma unroll
    for (int k = 0; k < K_; ++k)
        m_out[((size_t)(b*K_ + k) << 18) + p] = ex[k] * inv;
    const float* ip = img + ((size_t)(b*3) << 18) + p;
    atomicAdd(&bins[kstar*4+0], ip[0]);
    atomicAdd(&bins[kstar*4+1], ip[(size_t)1 << 18]);
    atomicAdd(&bins[kstar*4+2], ip[(size_t)2 << 18]);
    atomicAdd(&bins[kstar*4+3], 1.0f);
    __syncthreads();
    if (t < K_*4) atomicAdd(&accum[b*K_*4 + t], bins[t]);
}

__global__ __launch_bounds__(256) void recolor_m_kernel(
    const float* __restrict__ m_in, const float* __restrict__ palf,
    float* __restrict__ timg)
{
    int g = blockIdx.x*256 + threadIdx.x;
    int b = g >> 18, p = g & (HW_-1);
    const float* mp = m_in + ((size_t)(b*K_) << 18) + p;
    float best = -1.0f; int ks = 0;
#pragma unroll
    for (int k = 0; k < K_; ++k) {
        float v = mp[(size_t)k << 18];
        if (v > best) { best = v; ks = k; }
    }
#pragma unroll
    for (int c = 0; c < 3; ++c)
        timg[((size_t)(b*3+c) << 18) + p] = palf[(b*K_ + ks)*3 + c];
}

extern "C" void kernel_launch(void* const* d_in, const int* in_sizes, int n_in,
                              void* d_out, int out_size, void* d_ws, size_t ws_size,
                              hipStream_t stream)
{
    const float* img  = (const float*)d_in[0];
    const float* feat = (const float*)d_in[1];
    const float* W1   = (const float*)d_in[2];
    const float* b1   = (const float*)d_in[3];
    const float* W2   = (const float*)d_in[4];

    float* out0 = (float*)d_out;                  // transformed_img (B,3,H,W)
    float* out1 = out0 + (size_t)B_*3*HW_;        // m (B,K,H,W)
    float* out2 = out1 + (size_t)B_*K_*HW_;       // color_palette (B,K,3,1,1)
    float* wsf  = (float*)d_ws;

    if (ws_size >= WS_NEED_FAST) {
        const unsigned short* w1f = (const unsigned short*)((char*)d_ws + W1F_BYTE);
        const unsigned short* w2f = (const unsigned short*)((char*)d_ws + W2F_BYTE);
        int* lbl = (int*)((char*)d_ws + LBL_BYTE);
        float* palf = wsf + 256;                  // byte 1024
        prep_fast<<<48, 256, 0, stream>>>(W1, W2, wsf);
        mlp_mfma<<<NPIX/128, 256, 0, stream>>>(feat, img, b1,
                                               w1f, w2f, out1, wsf, lbl);
        palette_kernel<<<1, 64, 0, stream>>>(wsf, out2, palf);
        recolor_lbl_kernel<<<NPIX/256, 256, 0, stream>>>(lbl, palf, out0);
    } else {
        prep_scalar<<<1, 256, 0, stream>>>(W1, b1, W2, wsf);
        mlp_scalar<<<NPIX/256, 256, 0, stream>>>(feat, img, wsf, out1, wsf);
        palette_kernel<<<1, 64, 0, stream>>>(wsf, out2, wsf + 10624);
        recolor_m_kernel<<<NPIX/256, 256, 0, stream>>>(out1, wsf + 10624, out0);
    }
}